// Round 3
// baseline (202.238 us; speedup 1.0000x reference)
//
#include <hip/hip_runtime.h>

// out[r] = sum_{s in ray r} w[s] * rgb[s,:]  (segment_ids sorted, fp32)
// Wave-autonomous, barrier-free.
// v4: global_load_lds streaming. v2/v3 post-mortem: register-held prefetch is
// sunk by the register allocator (VGPR_Count 32/56 proves it) -> ~1 chunk in
// flight -> latency-bound at ~2.6 TB/s delivered. Fix: stage via
// __builtin_amdgcn_global_load_lds (in-flight bytes live in LDS, cost no
// VGPRs, ordered by explicit counted s_waitcnt that the compiler can't sink).
//   - each wave owns 2048 samples = 8 chunks x 256 samples
//   - 2 wave-private LDS buffers x 5 KB, depth-2 pipeline, 5 gll16/chunk
//   - main-loop wait = vmcnt(5): the 5 newest outstanding ops are always the
//     next chunk's stage (atomics are issued BEFORE the next stage, so they
//     are older and merely drain alongside -- counted wait stays safe for any
//     divergent atomic count)
//   - per chunk: per-lane run merge + 6-step segmented shuffle scan + one
//     atomicAdd triplet per run-end (out pre-zeroed)

#define NTHREADS 256
#define WAVES_PER_BLOCK (NTHREADS / 64)
#define CPL 4                      // samples per lane per chunk
#define CHUNK (64 * CPL)           // 256 samples
#define CHUNKS 8                   // chunks per wave span
#define SPW (CHUNK * CHUNKS)       // 2048 samples per wave
#define CHUNK_BYTES (CHUNK * 20)   // 5120 B: ids 1K | w 1K | rgb 3K
#define IDS_OFF 0
#define W_OFF 1024
#define RGB_OFF 2048

__global__ __launch_bounds__(NTHREADS) void zero_out_kernel(float4* __restrict__ out4,
                                                            int n4) {
  int i = blockIdx.x * blockDim.x + threadIdx.x;
  if (i < n4) out4[i] = make_float4(0.f, 0.f, 0.f, 0.f);
}

__device__ __forceinline__ void gll16(const void* g, void* l) {
  // moves 64 lanes x 16 B; LDS dest = wave-uniform base + lane*16
  __builtin_amdgcn_global_load_lds(
      (const __attribute__((address_space(1))) void*)g,
      (__attribute__((address_space(3))) void*)l, 16, 0, 0);
}

__device__ __forceinline__ void process_chunk(const int4 id4, const float4 w4,
                                              const float4 r0, const float4 r1,
                                              const float4 r2, const int lane,
                                              float* __restrict__ out) {
  int idv[CPL] = {id4.x, id4.y, id4.z, id4.w};
  float px[CPL], py[CPL], pz[CPL];
  px[0] = r0.x * w4.x; py[0] = r0.y * w4.x; pz[0] = r0.z * w4.x;
  px[1] = r0.w * w4.y; py[1] = r1.x * w4.y; pz[1] = r1.y * w4.y;
  px[2] = r1.z * w4.z; py[2] = r1.w * w4.z; pz[2] = r2.x * w4.z;
  px[3] = r2.y * w4.w; py[3] = r2.z * w4.w; pz[3] = r2.w * w4.w;

  // ---- per-lane sequential run merge (ids sorted within lane) ------------
  const int first_id = idv[0];
  int run_id = first_id;
  float rx = px[0], ry = py[0], rz = pz[0];
  float hx = 0.f, hy = 0.f, hz = 0.f;
  bool f_intra = false;
  #pragma unroll
  for (int k = 1; k < CPL; ++k) {
    if (idv[k] == run_id) {
      rx += px[k]; ry += py[k]; rz += pz[k];
    } else {
      if (!f_intra) {
        hx = rx; hy = ry; hz = rz; f_intra = true;  // stash head run
      } else {  // interior complete run (rare) -> direct flush
        atomicAdd(&out[3 * run_id + 0], rx);
        atomicAdd(&out[3 * run_id + 1], ry);
        atomicAdd(&out[3 * run_id + 2], rz);
      }
      run_id = idv[k];
      rx = px[k]; ry = py[k]; rz = pz[k];
    }
  }
  const int last_id = run_id;

  // ---- cross-lane segmented scan over tail partials ----------------------
  const int prev_tid = __shfl_up(last_id, 1, 64);
  int fl = (lane == 0 || f_intra || prev_tid != first_id) ? 1 : 0;
  float sx = rx, sy = ry, sz = rz;
  #pragma unroll
  for (int off = 1; off < 64; off <<= 1) {
    const float ox = __shfl_up(sx, off, 64);
    const float oy = __shfl_up(sy, off, 64);
    const float oz = __shfl_up(sz, off, 64);
    const int ofl = __shfl_up(fl, off, 64);
    if (lane >= off && fl == 0) { sx += ox; sy += oy; sz += oz; fl = ofl; }
  }

  // head-run flush
  const float pSx = __shfl_up(sx, 1, 64);
  const float pSy = __shfl_up(sy, 1, 64);
  const float pSz = __shfl_up(sz, 1, 64);
  if (f_intra) {
    const bool link = (lane > 0) && (prev_tid == first_id);
    atomicAdd(&out[3 * first_id + 0], hx + (link ? pSx : 0.f));
    atomicAdd(&out[3 * first_id + 1], hy + (link ? pSy : 0.f));
    atomicAdd(&out[3 * first_id + 2], hz + (link ? pSz : 0.f));
  }

  // tail-run flush
  const int next_hid = __shfl_down(first_id, 1, 64);
  if (lane == 63 || next_hid != last_id) {
    atomicAdd(&out[3 * last_id + 0], sx);
    atomicAdd(&out[3 * last_id + 1], sy);
    atomicAdd(&out[3 * last_id + 2], sz);
  }
}

__global__ __launch_bounds__(NTHREADS) void integrate_kernel(
    const int* __restrict__ ids, const float* __restrict__ rgb,
    const float* __restrict__ w, float* __restrict__ out, int n_samples) {
  __shared__ char lds[WAVES_PER_BLOCK * 2 * CHUNK_BYTES];  // 40 KB/block
  const int lane = threadIdx.x & 63;
  const int wib = threadIdx.x >> 6;
  char* mybuf = lds + wib * (2 * CHUNK_BYTES);  // wave-private, no barriers

  const long long wave_id = (long long)blockIdx.x * WAVES_PER_BLOCK + wib;
  const long long span0 = wave_id * SPW;
  if (span0 >= (long long)n_samples) return;

  if (span0 + SPW <= (long long)n_samples) {
    // ---- fast path: LDS-staged depth-2 stream ----------------------------
    const char* gid = (const char*)(ids + span0) + lane * 16;
    const char* gw  = (const char*)(w + span0) + lane * 16;
    const char* grg = (const char*)(rgb + 3 * span0) + lane * 16;

#define STAGE(c, b)                                                     \
    do {                                                                \
      const long long o_ = (long long)(c) * (CHUNK * 4);                \
      char* lb_ = mybuf + (b) * CHUNK_BYTES;                            \
      gll16(gid + o_, lb_ + IDS_OFF);                                   \
      gll16(gw + o_, lb_ + W_OFF);                                      \
      gll16(grg + 3 * o_, lb_ + RGB_OFF);                               \
      gll16(grg + 3 * o_ + 1024, lb_ + RGB_OFF + 1024);                 \
      gll16(grg + 3 * o_ + 2048, lb_ + RGB_OFF + 2048);                 \
    } while (0)

    STAGE(0, 0);
    STAGE(1, 1);
    #pragma unroll
    for (int c = 0; c < CHUNKS; ++c) {
      if (c < CHUNKS - 1) {
        // the 5 newest outstanding vmem ops are chunk c+1's stage ->
        // everything older (chunk c's stage + prior atomics) has retired
        asm volatile("s_waitcnt vmcnt(5)" ::: "memory");
      } else {
        asm volatile("s_waitcnt vmcnt(0)" ::: "memory");
      }
      const char* lb = mybuf + (c & 1) * CHUNK_BYTES;
      const int4   i4 = *(const int4*)(lb + IDS_OFF + lane * 16);
      const float4 w4 = *(const float4*)(lb + W_OFF + lane * 16);
      const float4 r0 = *(const float4*)(lb + RGB_OFF + lane * 48);
      const float4 r1 = *(const float4*)(lb + RGB_OFF + lane * 48 + 16);
      const float4 r2 = *(const float4*)(lb + RGB_OFF + lane * 48 + 32);
      process_chunk(i4, w4, r0, r1, r2, lane, out);  // atomics BEFORE next stage
      if (c + 2 < CHUNKS) {
        // LDS reads of this buffer complete before its re-stage can land
        asm volatile("s_waitcnt lgkmcnt(0)" ::: "memory");
        STAGE(c + 2, c & 1);
      }
    }
#undef STAGE
  } else {
    // ---- tail path: bounds-checked scalar gather (never hit when
    //      n_samples % SPW == 0, as in the bench) -------------------------
    const int last = ids[n_samples - 1];
    for (int c = 0; c < CHUNKS; ++c) {
      const long long cb = span0 + (long long)c * CHUNK;
      if (cb >= (long long)n_samples) break;  // wave-uniform
      int idt[CPL]; float wt[CPL], rt[3 * CPL];
      #pragma unroll
      for (int j = 0; j < CPL; ++j) {
        const long long s = cb + (long long)lane * CPL + j;
        if (s < (long long)n_samples) {
          idt[j] = ids[s];
          wt[j] = w[s];
          rt[3 * j + 0] = rgb[3 * s + 0];
          rt[3 * j + 1] = rgb[3 * s + 1];
          rt[3 * j + 2] = rgb[3 * s + 2];
        } else {
          idt[j] = (j == 0) ? last : idt[j - 1];
          wt[j] = 0.f;
          rt[3 * j + 0] = rt[3 * j + 1] = rt[3 * j + 2] = 0.f;
        }
      }
      const int4 i4 = make_int4(idt[0], idt[1], idt[2], idt[3]);
      const float4 w4 = make_float4(wt[0], wt[1], wt[2], wt[3]);
      const float4 r0 = make_float4(rt[0], rt[1], rt[2], rt[3]);
      const float4 r1 = make_float4(rt[4], rt[5], rt[6], rt[7]);
      const float4 r2 = make_float4(rt[8], rt[9], rt[10], rt[11]);
      process_chunk(i4, w4, r0, r1, r2, lane, out);
    }
  }
}

extern "C" void kernel_launch(void* const* d_in, const int* in_sizes, int n_in,
                              void* d_out, int out_size, void* d_ws, size_t ws_size,
                              hipStream_t stream) {
  const int*   segment_ids = (const int*)d_in[0];
  const float* rgb         = (const float*)d_in[1];
  const float* weights     = (const float*)d_in[2];
  float*       out         = (float*)d_out;

  const int n_samples = in_sizes[0];

  {  // zero output (all contributions arrive via atomics)
    int n4 = out_size / 4;
    int blocks = (n4 + NTHREADS - 1) / NTHREADS;
    zero_out_kernel<<<blocks, NTHREADS, 0, stream>>>((float4*)out, n4);
  }
  {
    long long waves = ((long long)n_samples + SPW - 1) / SPW;
    int blocks = (int)((waves + WAVES_PER_BLOCK - 1) / WAVES_PER_BLOCK);
    integrate_kernel<<<blocks, NTHREADS, 0, stream>>>(
        segment_ids, rgb, weights, out, n_samples);
  }
}